// Round 8
// baseline (138.625 us; speedup 1.0000x reference)
//
#include <hip/hip_runtime.h>
#include <math.h>

// X[8192,64], Y[8192,64] fp32.
// d2[i][j] = x2_i + y2_j - 2<x_i,y_j>;  out = mean_i sqrt(min_j d2) + mean_j sqrt(min_i d2)
//
// R8: mine has NO LDS and NO barriers — K=64 fits a 64x64 wave-tile's operands
// in registers (Af 8xb128 persistent, Bf 8xb128 per chunk loaded straight from
// the L2-resident bf16 copy). Every wave is an independent load->MFMA->epilogue
// pipeline; 3 waves/SIMD (lb 256,3; ~168 unified VGPR) cover each other's L2
// latency. prep: fp32->bf16 + squares. Slabs carry x2/y2 folded in; every slot
// written exactly once (poison-safe, no atomics). finish: coalesced reduction.
// Fixed floor: harness's 268 MB d_ws 0xAA re-poison (~41 us) is in the timed
// window.

#define NROWS 8192
#define DDIM  64
#define ITILES 64
#define SLICES 32     // j: 32 slices x 256
#define CHUNKS 2      // 2 x 128 j per block

typedef __bf16 bf16_t;
typedef bf16_t bf16x8 __attribute__((ext_vector_type(8)));
typedef float  f32x4  __attribute__((ext_vector_type(4)));

// ws: bf16 Xbf 1MB | Ybf 1MB | floats x2[8192] y2[8192] |
//     rslab[32][8192][2] 2MB | cslab[128][8192] 4MB

__global__ void prep_kernel(const float* __restrict__ X,
                            const float* __restrict__ Y,
                            bf16_t* __restrict__ Xbf, bf16_t* __restrict__ Ybf,
                            float* __restrict__ x2, float* __restrict__ y2,
                            float* __restrict__ out) {
  int t = blockIdx.x * blockDim.x + threadIdx.x;   // 0..65535
  int half = t >> 15;                              // 0: X, 1: Y
  int r = (t >> 2) & (NROWS - 1);
  int part = t & 3;                                // 16 elems per thread
  const float* src = half ? Y : X;
  bf16_t* dst = half ? Ybf : Xbf;
  float* sq = half ? y2 : x2;

  const float4* p = (const float4*)(src + r * DDIM + part * 16);
  float4 v0 = p[0], v1 = p[1], v2 = p[2], v3 = p[3];
  float s = 0.f;
  s = fmaf(v0.x, v0.x, s); s = fmaf(v0.y, v0.y, s);
  s = fmaf(v0.z, v0.z, s); s = fmaf(v0.w, v0.w, s);
  s = fmaf(v1.x, v1.x, s); s = fmaf(v1.y, v1.y, s);
  s = fmaf(v1.z, v1.z, s); s = fmaf(v1.w, v1.w, s);
  s = fmaf(v2.x, v2.x, s); s = fmaf(v2.y, v2.y, s);
  s = fmaf(v2.z, v2.z, s); s = fmaf(v2.w, v2.w, s);
  s = fmaf(v3.x, v3.x, s); s = fmaf(v3.y, v3.y, s);
  s = fmaf(v3.z, v3.z, s); s = fmaf(v3.w, v3.w, s);

  bf16x8 h0 = {(bf16_t)v0.x, (bf16_t)v0.y, (bf16_t)v0.z, (bf16_t)v0.w,
               (bf16_t)v1.x, (bf16_t)v1.y, (bf16_t)v1.z, (bf16_t)v1.w};
  bf16x8 h1 = {(bf16_t)v2.x, (bf16_t)v2.y, (bf16_t)v2.z, (bf16_t)v2.w,
               (bf16_t)v3.x, (bf16_t)v3.y, (bf16_t)v3.z, (bf16_t)v3.w};
  *(bf16x8*)&dst[r * DDIM + part * 16] = h0;
  *(bf16x8*)&dst[r * DDIM + part * 16 + 8] = h1;

  s += __shfl_xor(s, 1, 64);
  s += __shfl_xor(s, 2, 64);
  if (part == 0) sq[r] = s;
  if (t == 0) out[0] = 0.f;
}

__global__ __launch_bounds__(256, 3)
void mine_kernel(const bf16_t* __restrict__ Xbf, const bf16_t* __restrict__ Ybf,
                 const float* __restrict__ x2g, const float* __restrict__ y2g,
                 float* __restrict__ rslab, float* __restrict__ cslab) {
  const int tid = threadIdx.x;
  const int L = tid & 63;
  const int w = tid >> 6;
  const int lr = L & 15;
  const int q  = L >> 4;
  const int rh = w >> 1, ch = w & 1;
  const int itile = blockIdx.x & (ITILES - 1);
  const int slice = blockIdx.x >> 6;        // 0..31
  const int i0 = itile * 128;
  const int rgb = rh * 64, cgb = ch * 64;
  const int jbase = slice * (CHUNKS * 128);

  // ---- A fragments: register-persistent, direct from L2 ----
  bf16x8 Af[8];
#pragma unroll
  for (int a = 0; a < 4; ++a) {
    const bf16_t* rp = Xbf + (i0 + rgb + a * 16 + lr) * DDIM + q * 8;
    Af[a * 2 + 0] = *(const bf16x8*)(rp);
    Af[a * 2 + 1] = *(const bf16x8*)(rp + 32);
  }
  float x2acc[4];                       // x2 of row a*16+lr (shfl at use)
#pragma unroll
  for (int a = 0; a < 4; ++a) x2acc[a] = x2g[i0 + rgb + a * 16 + lr];

  float rmin[16];
#pragma unroll
  for (int k = 0; k < 16; ++k) rmin[k] = INFINITY;

#pragma unroll
  for (int cc = 0; cc < CHUNKS; ++cc) {
    const int j0 = jbase + cc * 128;

    // ---- B fragments: direct global->VGPR, all 8 loads in flight ----
    bf16x8 Bf[8];
#pragma unroll
    for (int b = 0; b < 4; ++b) {
      const bf16_t* cp = Ybf + (j0 + cgb + b * 16 + lr) * DDIM + q * 8;
      Bf[b * 2 + 0] = *(const bf16x8*)(cp);
      Bf[b * 2 + 1] = *(const bf16x8*)(cp + 32);
    }
    float y2c[4];
#pragma unroll
    for (int b = 0; b < 4; ++b) y2c[b] = y2g[j0 + cgb + b * 16 + lr];

    f32x4 acc[4][4];
#pragma unroll
    for (int a = 0; a < 4; ++a)
#pragma unroll
      for (int b = 0; b < 4; ++b) acc[a][b] = (f32x4){0.f, 0.f, 0.f, 0.f};

#pragma unroll
    for (int h = 0; h < 2; ++h)
#pragma unroll
      for (int b = 0; b < 4; ++b)
#pragma unroll
        for (int a = 0; a < 4; ++a)
          acc[a][b] = __builtin_amdgcn_mfma_f32_16x16x32_bf16(
              Af[a * 2 + h], Bf[b * 2 + h], acc[a][b], 0, 0, 0);

    // ---- epilogue (C/D: col = lr within 16-group, row = q*4+p) ----
    float cmin[4] = {INFINITY, INFINITY, INFINITY, INFINITY};
#pragma unroll
    for (int a = 0; a < 4; ++a)
#pragma unroll
      for (int p = 0; p < 4; ++p) {
        float x2v = __shfl(x2acc[a], q * 4 + p, 64);
        float t0 = fmaf(-2.f, acc[a][0][p], y2c[0]);
        float t1 = fmaf(-2.f, acc[a][1][p], y2c[1]);
        float t2 = fmaf(-2.f, acc[a][2][p], y2c[2]);
        float t3 = fmaf(-2.f, acc[a][3][p], y2c[3]);
        rmin[a * 4 + p] = fminf(rmin[a * 4 + p],
                                fminf(fminf(t0, t1), fminf(t2, t3)));
        cmin[0] = fminf(cmin[0], fmaf(-2.f, acc[a][0][p], x2v));
        cmin[1] = fminf(cmin[1], fmaf(-2.f, acc[a][1][p], x2v));
        cmin[2] = fminf(cmin[2], fmaf(-2.f, acc[a][2][p], x2v));
        cmin[3] = fminf(cmin[3], fmaf(-2.f, acc[a][3][p], x2v));
      }
#pragma unroll
    for (int b = 0; b < 4; ++b) {
      cmin[b] = fminf(cmin[b], __shfl_xor(cmin[b], 16, 64));
      cmin[b] = fminf(cmin[b], __shfl_xor(cmin[b], 32, 64));
    }
    float v = cmin[0], yv = y2c[0];
    if (q == 1) { v = cmin[1]; yv = y2c[1]; }
    else if (q == 2) { v = cmin[2]; yv = y2c[2]; }
    else if (q == 3) { v = cmin[3]; yv = y2c[3]; }
    cslab[(itile * 2 + rh) * NROWS + j0 + cgb + L] = v + yv;  // y2 folded
  }

  // ---- row mins: reduce across 16 col-lanes, fold x2, store once ----
#pragma unroll
  for (int a = 0; a < 4; ++a)
#pragma unroll
    for (int p = 0; p < 4; ++p) {
      float v = rmin[a * 4 + p];
      v = fminf(v, __shfl_xor(v, 1, 64));
      v = fminf(v, __shfl_xor(v, 2, 64));
      v = fminf(v, __shfl_xor(v, 4, 64));
      v = fminf(v, __shfl_xor(v, 8, 64));
      float x2v = __shfl(x2acc[a], q * 4 + p, 64);
      if (lr == 0)
        rslab[slice * (NROWS * 2) + (i0 + rgb + a * 16 + q * 4 + p) * 2 + ch] =
            v + x2v;
    }
}

// blocks [0,32): rows (256 each, 32x float2 coalesced). [32,160): cols
// (64 each, 4 segments x 32 partials, LDS combine). Slabs include x2/y2.
__global__ void finish_kernel(const float* __restrict__ rslab,
                              const float* __restrict__ cslab,
                              float* __restrict__ out) {
  const int b = blockIdx.x;
  const int tid = threadIdx.x;
  if (b < 32) {
    int row = b * 256 + tid;
    float m = INFINITY;
#pragma unroll
    for (int g = 0; g < SLICES; ++g) {
      float2 v = *(const float2*)&rslab[g * (NROWS * 2) + row * 2];
      m = fminf(m, fminf(v.x, v.y));
    }
    float v = sqrtf(fmaxf(m, 0.f)) * (1.0f / 8192.0f);
#pragma unroll
    for (int off = 32; off > 0; off >>= 1) v += __shfl_down(v, off, 64);
    __shared__ float partial[4];
    if ((tid & 63) == 0) partial[tid >> 6] = v;
    __syncthreads();
    if (tid == 0)
      atomicAdd(out, partial[0] + partial[1] + partial[2] + partial[3]);
  } else {
    int j = (b - 32) * 64 + (tid & 63);
    int seg = tid >> 6;
    float m = INFINITY;
#pragma unroll
    for (int k = 0; k < 32; ++k)
      m = fminf(m, cslab[(seg * 32 + k) * NROWS + j]);
    __shared__ float red[4][64];
    red[seg][tid & 63] = m;
    __syncthreads();
    if (tid < 64) {
      float mc = fminf(fminf(red[0][tid], red[1][tid]),
                       fminf(red[2][tid], red[3][tid]));
      float v = sqrtf(fmaxf(mc, 0.f)) * (1.0f / 8192.0f);
#pragma unroll
      for (int off = 32; off > 0; off >>= 1) v += __shfl_down(v, off, 64);
      if (tid == 0) atomicAdd(out, v);
    }
  }
}

extern "C" void kernel_launch(void* const* d_in, const int* in_sizes, int n_in,
                              void* d_out, int out_size, void* d_ws, size_t ws_size,
                              hipStream_t stream) {
  const float* X = (const float*)d_in[0];
  const float* Y = (const float*)d_in[1];
  float* out = (float*)d_out;

  char* wsb = (char*)d_ws;
  bf16_t* Xbf = (bf16_t*)wsb;                                // 1 MB
  bf16_t* Ybf = (bf16_t*)(wsb + (size_t)NROWS * DDIM * 2);   // 1 MB
  float* x2 = (float*)(wsb + 2 * (size_t)NROWS * DDIM * 2);
  float* y2 = x2 + NROWS;
  float* rslab = y2 + NROWS;                    // [32][8192][2]  2 MB
  float* cslab = rslab + SLICES * NROWS * 2;    // [128][8192]    4 MB

  prep_kernel<<<(2 * NROWS * 4) / 256, 256, 0, stream>>>(X, Y, Xbf, Ybf, x2, y2, out);
  mine_kernel<<<ITILES * SLICES, 256, 0, stream>>>(Xbf, Ybf, x2, y2, rslab, cslab);
  finish_kernel<<<160, 256, 0, stream>>>(rslab, cslab, out);
}